// Round 1
// baseline (152.962 us; speedup 1.0000x reference)
//
#include <hip/hip_runtime.h>

// AttentionPooling: out[b,:] = sum_l softmax_l(tanh(dot(keys[b,l,:], q[b,:]*W))) * keys[b,l,:]
// B=16384, L=200, D=64, all fp32.
//
// One wave (64 lanes) per batch element. Each lane loads float4 -> one wave
// load covers 4 rows (1KB contiguous). Lane i holds row (i>>4), dims
// ((i&15)*4 .. +3). Scores reduced within 16-lane groups (4 shfl_xor).
// tanh in (-1,1) => exp(tanh) in [1/e, e]: no online-max needed, plain
// running sum softmax. Single pass over keys => memory-bound at ~134us.

#define B_TOTAL 16384
#define L_ROWS  200
#define D_DIM   64

__global__ __launch_bounds__(256)
void attn_pool_kernel(const float* __restrict__ query,
                      const float* __restrict__ keys,
                      const float* __restrict__ W,
                      float* __restrict__ out)
{
    const int wave = threadIdx.x >> 6;   // 0..3
    const int lane = threadIdx.x & 63;
    const int b = blockIdx.x * 4 + wave; // grid sized exactly: no bounds check

    const int d0 = (lane & 15) * 4;      // dim offset this lane owns

    // qw = query[b, d0..d0+3] * W[d0..d0+3]   (broadcast across the 4 row-groups)
    float4 q4 = *reinterpret_cast<const float4*>(query + (size_t)b * D_DIM + d0);
    float4 w4 = *reinterpret_cast<const float4*>(W + d0);
    const float qwx = q4.x * w4.x;
    const float qwy = q4.y * w4.y;
    const float qwz = q4.z * w4.z;
    const float qww = q4.w * w4.w;

    const float4* kp = reinterpret_cast<const float4*>(keys + (size_t)b * (L_ROWS * D_DIM));

    float accx = 0.f, accy = 0.f, accz = 0.f, accw = 0.f;
    float wsum = 0.f;

    // 50 iterations, 4 rows each; L=200 divides exactly (no tail).
    #pragma unroll 2
    for (int i = 0; i < L_ROWS / 4; ++i) {
        float4 k4 = kp[i * 64 + lane];   // wave reads 1KB contiguous

        // partial dot over this lane's 4 dims
        float p = k4.x * qwx + k4.y * qwy + k4.z * qwz + k4.w * qww;
        // reduce across the 16-lane group that shares this row
        p += __shfl_xor(p, 1);
        p += __shfl_xor(p, 2);
        p += __shfl_xor(p, 4);
        p += __shfl_xor(p, 8);
        // p = pre-activation score for row i*4 + (lane>>4)

        // w = exp(tanh(p)); tanh via e = exp(2p): t = (e-1)/(e+1)
        float e = __expf(2.0f * p);
        float t = (e - 1.0f) * __builtin_amdgcn_rcpf(e + 1.0f);
        float wgt = __expf(t);

        wsum += wgt;
        accx = fmaf(wgt, k4.x, accx);
        accy = fmaf(wgt, k4.y, accy);
        accz = fmaf(wgt, k4.z, accz);
        accw = fmaf(wgt, k4.w, accw);
    }

    // combine the 4 row-groups (lanes i, i+16, i+32, i+48 own identical dims)
    #pragma unroll
    for (int m = 16; m <= 32; m <<= 1) {
        accx += __shfl_xor(accx, m);
        accy += __shfl_xor(accy, m);
        accz += __shfl_xor(accz, m);
        accw += __shfl_xor(accw, m);
        wsum += __shfl_xor(wsum, m);
    }

    if (lane < 16) {
        float inv = __builtin_amdgcn_rcpf(wsum);
        float4 o;
        o.x = accx * inv;
        o.y = accy * inv;
        o.z = accz * inv;
        o.w = accw * inv;
        reinterpret_cast<float4*>(out + (size_t)b * D_DIM)[lane] = o;
    }
}

extern "C" void kernel_launch(void* const* d_in, const int* in_sizes, int n_in,
                              void* d_out, int out_size, void* d_ws, size_t ws_size,
                              hipStream_t stream) {
    const float* query = (const float*)d_in[0]; // [B, D]
    const float* keys  = (const float*)d_in[1]; // [B, L, D]
    const float* W     = (const float*)d_in[2]; // [1, D]
    float* out = (float*)d_out;                 // [B, D]

    dim3 grid(B_TOTAL / 4);   // 4096 blocks x 4 waves = 16384 waves = B
    dim3 block(256);
    hipLaunchKernelGGL(attn_pool_kernel, grid, block, 0, stream,
                       query, keys, W, out);
}

// Round 3
// 134.178 us; speedup vs baseline: 1.1400x; 1.1400x over previous
//
#include <hip/hip_runtime.h>

// AttentionPooling: out[b,:] = sum_l softmax_l(tanh(dot(keys[b,l,:], q[b,:]*W))) * keys[b,l,:]
// B=16384, L=200, D=64, all fp32. Memory-bound: 847 MB single pass, floor ~125-134us.
//
// One wave per batch element. Lane i holds row (i>>4), dims ((i&15)*4..+3);
// one wave-load = 4 rows = 1KB contiguous. tanh in (-1,1) => exp in [1/e,e]:
// no online max needed, plain running-sum softmax => single pass over keys.
//
// NB=5 software pipeline: 5 loads issued back-to-back (MLP), then 5
// INDEPENDENT 4-step shfl_xor reduce chains interleaved so DS ops pipeline
// instead of serializing. Keys via nontemporal loads (839MB stream, zero
// reuse -- don't thrash L2/L3). ext_vector float4 (not HIP_vector_type)
// because __builtin_nontemporal_load requires a true clang vector type.

#define B_TOTAL 16384
#define L_ROWS  200
#define D_DIM   64
#define NB      5     // row-groups per pipelined iteration; (L/4)/NB = 10 exact

typedef float f32x4 __attribute__((ext_vector_type(4)));

__global__ __launch_bounds__(256)
void attn_pool_kernel(const float* __restrict__ query,
                      const float* __restrict__ keys,
                      const float* __restrict__ W,
                      float* __restrict__ out)
{
    const int wave = threadIdx.x >> 6;   // 0..3
    const int lane = threadIdx.x & 63;
    const int b = blockIdx.x * 4 + wave; // grid sized exactly: no bounds check

    const int d0 = (lane & 15) * 4;      // dim offset this lane owns

    f32x4 q4 = *reinterpret_cast<const f32x4*>(query + (size_t)b * D_DIM + d0);
    f32x4 w4 = *reinterpret_cast<const f32x4*>(W + d0);
    const float qwx = q4.x * w4.x;
    const float qwy = q4.y * w4.y;
    const float qwz = q4.z * w4.z;
    const float qww = q4.w * w4.w;

    const f32x4* kp = reinterpret_cast<const f32x4*>(keys + (size_t)b * (L_ROWS * D_DIM)) + lane;

    float accx = 0.f, accy = 0.f, accz = 0.f, accw = 0.f;
    float wsum = 0.f;

    for (int i = 0; i < (L_ROWS / 4) / NB; ++i) {
        // batch the loads: NB independent dwordx4 in flight
        f32x4 k[NB];
        #pragma unroll
        for (int j = 0; j < NB; ++j)
            k[j] = __builtin_nontemporal_load(kp + (i * NB + j) * 64);

        // partial dots over this lane's 4 dims
        float p[NB];
        #pragma unroll
        for (int j = 0; j < NB; ++j)
            p[j] = k[j].x * qwx + k[j].y * qwy + k[j].z * qwz + k[j].w * qww;

        // 16-lane-group reduction: NB independent chains interleaved,
        // so the 4 DS-swizzle steps pipeline across chains
        #pragma unroll
        for (int m = 1; m <= 8; m <<= 1) {
            #pragma unroll
            for (int j = 0; j < NB; ++j)
                p[j] += __shfl_xor(p[j], m);
        }

        // wgt = exp(tanh(p)); tanh via e=exp(2p): t=(e-1)/(e+1)
        #pragma unroll
        for (int j = 0; j < NB; ++j) {
            float e = __expf(2.0f * p[j]);
            float t = (e - 1.0f) * __builtin_amdgcn_rcpf(e + 1.0f);
            float wgt = __expf(t);
            wsum += wgt;
            accx = fmaf(wgt, k[j].x, accx);
            accy = fmaf(wgt, k[j].y, accy);
            accz = fmaf(wgt, k[j].z, accz);
            accw = fmaf(wgt, k[j].w, accw);
        }
    }

    // combine the 4 row-groups (lanes i, i+16, i+32, i+48 own identical dims)
    #pragma unroll
    for (int m = 16; m <= 32; m <<= 1) {
        accx += __shfl_xor(accx, m);
        accy += __shfl_xor(accy, m);
        accz += __shfl_xor(accz, m);
        accw += __shfl_xor(accw, m);
        wsum += __shfl_xor(wsum, m);
    }

    if (lane < 16) {
        float inv = __builtin_amdgcn_rcpf(wsum);
        f32x4 o;
        o.x = accx * inv;
        o.y = accy * inv;
        o.z = accz * inv;
        o.w = accw * inv;
        *reinterpret_cast<f32x4*>(out + (size_t)b * D_DIM + lane * 4) = o;
    }
}

extern "C" void kernel_launch(void* const* d_in, const int* in_sizes, int n_in,
                              void* d_out, int out_size, void* d_ws, size_t ws_size,
                              hipStream_t stream) {
    const float* query = (const float*)d_in[0]; // [B, D]
    const float* keys  = (const float*)d_in[1]; // [B, L, D]
    const float* W     = (const float*)d_in[2]; // [1, D]
    float* out = (float*)d_out;                 // [B, D]

    dim3 grid(B_TOTAL / 4);   // 4096 blocks x 4 waves = 16384 waves = B
    dim3 block(256);
    hipLaunchKernelGGL(attn_pool_kernel, grid, block, 0, stream,
                       query, keys, W, out);
}